// Round 7
// baseline (27216.541 us; speedup 1.0000x reference)
//
#include <hip/hip_runtime.h>

// Seq2Seq forward. External f32 (runtime-probed; bf16 path too); internal bf16
// MFMA + f32 state. R7: fixes R6's P6 ctx-staging index bug (read batch bb+1's
// context for the upper 256 K-rows); otherwise identical to R6's fused design:
// persistent encoder (1 dispatch) + persistent decoder (1 dispatch, 7 grid
// barriers/step via agent-scope flags).

#define DI __device__ __forceinline__

constexpr int BATCH = 32;
constexpr int TS = 1024;
constexpr int TG = 64;
constexpr int HID = 512;
constexpr int GD = 2048;
constexpr int EDIM = 256;
constexpr int SPECIAL = 4;
constexpr size_t OFF_H = (size_t)BATCH * TG * EDIM;
constexpr size_t OFF_C = OFF_H + (size_t)BATCH * TG * HID;
constexpr int FLAG_STRIDE = 16;   // dwords (64B) per flag

typedef __attribute__((ext_vector_type(8))) short bf16x8;
typedef __attribute__((ext_vector_type(4))) float f32x4;

DI float b2f(unsigned short u) {
  union { unsigned int i; float f; } v; v.i = ((unsigned int)u) << 16; return v.f;
}
DI unsigned short f2b(float f) {
  union { float f; unsigned int i; } v; v.f = f;
  unsigned int r = v.i + 0x7fffu + ((v.i >> 16) & 1u);
  return (unsigned short)(r >> 16);
}
DI float sigm(float x) { return 1.0f / (1.0f + expf(-x)); }
DI float ldf(const void* p, size_t i, int f32f) {
  return f32f ? ((const float*)p)[i] : b2f(((const unsigned short*)p)[i]);
}
DI void stf(void* p, size_t i, float v, int f32f) {
  if (f32f) ((float*)p)[i] = v; else ((unsigned short*)p)[i] = f2b(v);
}
DI unsigned int ald(const unsigned int* p) {
  return __hip_atomic_load(p, __ATOMIC_RELAXED, __HIP_MEMORY_SCOPE_AGENT);
}
DI float aldf(const float* p) {
  return __hip_atomic_load(p, __ATOMIC_RELAXED, __HIP_MEMORY_SCOPE_AGENT);
}
DI void ast(unsigned int* p, unsigned int v) {
  __hip_atomic_store(p, v, __ATOMIC_RELAXED, __HIP_MEMORY_SCOPE_AGENT);
}
DI void astf(float* p, float v) {
  __hip_atomic_store(p, v, __ATOMIC_RELAXED, __HIP_MEMORY_SCOPE_AGENT);
}

__global__ void detect_k(const void* art, int* flag) {
  int tid = threadIdx.x;
  float x = ((const float*)art)[tid + 1024];
  float a = fabsf(x);
  int sane = (x == 0.0f) || (a > 1e-8f && a < 1e4f);
  unsigned long long m = __ballot(sane);
  __shared__ int cnt[4];
  if ((tid & 63) == 0) cnt[tid >> 6] = __popcll(m);
  __syncthreads();
  if (tid == 0) flag[0] = (cnt[0] + cnt[1] + cnt[2] + cnt[3] > 128) ? 1 : 0;
}

__global__ void fill_sig_k(unsigned short* o, int n) {
  int g = blockIdx.x * 256 + threadIdx.x;
  if (g < n) o[g] = 0x42F6;
}

__global__ void pack_gate_k(const void* __restrict__ W,
                            unsigned short* __restrict__ pk, const int* dtf) {
  int f32f = dtf[0];
  int g = blockIdx.x * 256 + threadIdx.x;
  if (g >= (GD * HID) / 8) return;
  int lane = g & 63;
  int kk = (g >> 6) & 15;
  int tile = g >> 10;
  int p = tile * 16 + (lane & 15);
  int nloc = p & 63, blk = p >> 6;
  int orow = (nloc >> 4) * HID + blk * 16 + (nloc & 15);
  int k = kk * 32 + (lane >> 4) * 8;
  unsigned short tmp[8];
#pragma unroll
  for (int j = 0; j < 8; ++j) tmp[j] = f2b(ldf(W, (size_t)orow * HID + k + j, f32f));
  *(uint4*)(pk + (size_t)g * 8) = *(uint4*)tmp;
}

__global__ void pack_wm_k(const void* __restrict__ wm,
                          unsigned short* __restrict__ pk, const int* dtf) {
  int f32f = dtf[0];
  int g = blockIdx.x * 256 + threadIdx.x;
  if (g >= 32 * 32 * 64) return;
  int lane = g & 63;
  int kk = (g >> 6) & 31;
  int nt = g >> 11;
  int col = nt * 16 + (lane & 15);
  int kb = kk * 32 + (lane >> 4) * 8;
  unsigned short tmp[8];
#pragma unroll
  for (int j = 0; j < 8; ++j) tmp[j] = f2b(ldf(wm, (size_t)(kb + j) * HID + col, f32f));
  *(uint4*)(pk + (size_t)g * 8) = *(uint4*)tmp;
}

// ---------------------------------------------------------------------------
// Persistent bidirectional encoder (unchanged from R5 — proven).
// ---------------------------------------------------------------------------
__global__ __launch_bounds__(256, 1) void enc_all_k(
    const void* __restrict__ article,
    unsigned short* __restrict__ outF, unsigned short* __restrict__ outB,
    const unsigned short* __restrict__ hIF, const unsigned short* __restrict__ hIB,
    float* __restrict__ cF, float* __restrict__ cB,
    const unsigned short* __restrict__ pkXF, const unsigned short* __restrict__ pkHF,
    const unsigned short* __restrict__ pkXB, const unsigned short* __restrict__ pkHB,
    const void* __restrict__ bF, const void* __restrict__ bB,
    int* __restrict__ bar, const int* dtf) {
  const int f32f = dtf[0];
  const int blk = blockIdx.x;
  const int dir = blk >> 5;
  const int blk16 = blk & 31;
  const int tid = threadIdx.x;
  const int lane = tid & 63;
  const int wv = tid >> 6;
  const int tile = blk16 * 4 + wv;

  __shared__ unsigned short lstage[BATCH * HID];
  __shared__ float gbuf[BATCH * 68];

  const unsigned short* pkX = dir ? pkXB : pkXF;
  const unsigned short* pkH = dir ? pkHB : pkHF;
  const void* bias = dir ? bB : bF;
  unsigned short* out = dir ? outB : outF;
  const unsigned short* hI = dir ? hIB : hIF;
  float* cg = dir ? cB : cF;
  int* flp = bar + dir * 32 * FLAG_STRIDE;

  bf16x8 wx[16], wh[16];
  {
    const unsigned short* px = pkX + ((size_t)tile * 16 * 64 + lane) * 8;
    const unsigned short* ph = pkH + ((size_t)tile * 16 * 64 + lane) * 8;
#pragma unroll
    for (int kk = 0; kk < 16; ++kk) {
      wx[kk] = *(const bf16x8*)(px + (size_t)kk * 64 * 8);
      wh[kk] = *(const bf16x8*)(ph + (size_t)kk * 64 * 8);
    }
  }
  const int gb = tid >> 3;
  const int gj = (tid & 7) * 2;
  float c0 = cg[gb * HID + blk16 * 16 + gj];
  float c1 = cg[gb * HID + blk16 * 16 + gj + 1];

  const int r0 = lane & 15;
  const int r1 = 16 + r0;
  const int kbb = (lane >> 4) * 8;
  const int nloc = wv * 16 + (lane & 15);
  const int orow = (nloc >> 4) * HID + blk16 * 16 + (nloc & 15);
  const float bv = ldf(bias, orow, f32f);

  for (int t = 0; t < TS; ++t) {
    const int tsrc = dir ? (TS - 1 - t) : t;
#pragma unroll
    for (int it = 0; it < 8; ++it) {
      int ci = it * 256 + tid;
      int row = ci >> 6;
      int k8 = (ci & 63) << 3;
      unsigned off = (unsigned)(row * 1024 + ((k8 * 2) ^ ((row & 7) << 4)));
      if (f32f) {
        const float* s = (const float*)article + (size_t)tsrc * BATCH * HID +
                         (size_t)row * HID + k8;
        float4 u0 = *(const float4*)s;
        float4 u1 = *(const float4*)(s + 4);
        unsigned short tmp[8] = {f2b(u0.x), f2b(u0.y), f2b(u0.z), f2b(u0.w),
                                 f2b(u1.x), f2b(u1.y), f2b(u1.z), f2b(u1.w)};
        *(uint4*)((char*)lstage + off) = *(uint4*)tmp;
      } else {
        const unsigned short* s = (const unsigned short*)article +
                                  (size_t)tsrc * BATCH * HID + (size_t)row * HID + k8;
        *(uint4*)((char*)lstage + off) = *(const uint4*)s;
      }
    }
    __syncthreads();
    unsigned int* hu = (t == 0)
        ? (unsigned int*)hI
        : (unsigned int*)(out + (size_t)(tsrc + (dir ? 1 : -1)) * BATCH * HID);
    unsigned int hreg[32];
#pragma unroll
    for (int it = 0; it < 32; ++it) hreg[it] = ald(hu + it * 256 + tid);
    f32x4 acc0 = {0.f, 0.f, 0.f, 0.f};
    f32x4 acc1 = {0.f, 0.f, 0.f, 0.f};
#pragma unroll
    for (int kk = 0; kk < 16; ++kk) {
      unsigned o0 = (unsigned)(r0 * 1024 + (((kk * 32 + kbb) * 2) ^ ((r0 & 7) << 4)));
      unsigned o1 = (unsigned)(r1 * 1024 + (((kk * 32 + kbb) * 2) ^ ((r0 & 7) << 4)));
      bf16x8 a0 = *(const bf16x8*)((const char*)lstage + o0);
      bf16x8 a1 = *(const bf16x8*)((const char*)lstage + o1);
      acc0 = __builtin_amdgcn_mfma_f32_16x16x32_bf16(a0, wx[kk], acc0, 0, 0, 0);
      acc1 = __builtin_amdgcn_mfma_f32_16x16x32_bf16(a1, wx[kk], acc1, 0, 0, 0);
    }
    __syncthreads();
#pragma unroll
    for (int it = 0; it < 32; ++it) {
      int dw = it * 256 + tid;
      int row = dw >> 8;
      unsigned lb = (unsigned)(row * 1024 +
                               (((dw & 252) << 2) ^ ((row & 7) << 4)) +
                               ((dw & 3) << 2));
      *(unsigned int*)((char*)lstage + lb) = hreg[it];
    }
    __syncthreads();
#pragma unroll
    for (int kk = 0; kk < 16; ++kk) {
      unsigned o0 = (unsigned)(r0 * 1024 + (((kk * 32 + kbb) * 2) ^ ((r0 & 7) << 4)));
      unsigned o1 = (unsigned)(r1 * 1024 + (((kk * 32 + kbb) * 2) ^ ((r0 & 7) << 4)));
      bf16x8 a0 = *(const bf16x8*)((const char*)lstage + o0);
      bf16x8 a1 = *(const bf16x8*)((const char*)lstage + o1);
      acc0 = __builtin_amdgcn_mfma_f32_16x16x32_bf16(a0, wh[kk], acc0, 0, 0, 0);
      acc1 = __builtin_amdgcn_mfma_f32_16x16x32_bf16(a1, wh[kk], acc1, 0, 0, 0);
    }
#pragma unroll
    for (int r = 0; r < 4; ++r) {
      int brow = (lane >> 4) * 4 + r;
      gbuf[brow * 68 + nloc] = acc0[r] + bv;
      gbuf[(16 + brow) * 68 + nloc] = acc1[r] + bv;
    }
    __syncthreads();
    {
      float gi0 = gbuf[gb * 68 + gj],      gf0 = gbuf[gb * 68 + 16 + gj];
      float gg0 = gbuf[gb * 68 + 32 + gj], go0 = gbuf[gb * 68 + 48 + gj];
      float gi1 = gbuf[gb * 68 + gj + 1],      gf1 = gbuf[gb * 68 + 16 + gj + 1];
      float gg1 = gbuf[gb * 68 + 32 + gj + 1], go1 = gbuf[gb * 68 + 48 + gj + 1];
      float cn0 = sigm(gf0) * c0 + sigm(gi0) * tanhf(gg0); c0 = cn0;
      float cn1 = sigm(gf1) * c1 + sigm(gi1) * tanhf(gg1); c1 = cn1;
      unsigned int hv = (unsigned int)f2b(sigm(go0) * tanhf(cn0)) |
                        ((unsigned int)f2b(sigm(go1) * tanhf(cn1)) << 16);
      ast((unsigned int*)out + (size_t)tsrc * (BATCH * HID / 2) +
              gb * (HID / 2) + blk16 * 8 + (tid & 7), hv);
    }
    if (t + 1 < TS) {
      __syncthreads();
      if (wv == 0) {
        const int target = t + 1;
        if (lane == 0)
          __hip_atomic_store(flp + blk16 * FLAG_STRIDE, target,
                             __ATOMIC_RELAXED, __HIP_MEMORY_SCOPE_AGENT);
        for (;;) {
          int v = (lane < 32)
              ? __hip_atomic_load(flp + lane * FLAG_STRIDE, __ATOMIC_RELAXED,
                                  __HIP_MEMORY_SCOPE_AGENT)
              : 0x7fffffff;
          if (__all(v >= target)) break;
          __builtin_amdgcn_s_sleep(2);
        }
      }
      __syncthreads();
    }
  }
  cg[gb * HID + blk16 * 16 + gj] = c0;
  cg[gb * HID + blk16 * 16 + gj + 1] = c1;
}

// ---------------------------------------------------------------------------
// Persistent fused decoder: 256 blocks, 64 steps x 7 phases.
// ---------------------------------------------------------------------------
__global__ __launch_bounds__(256, 1) void dec_all_k(
    unsigned short* __restrict__ xdec,
    unsigned short* __restrict__ hd0, unsigned short* __restrict__ hd1,
    const float* __restrict__ cdec,
    const unsigned short* __restrict__ pkX, const unsigned short* __restrict__ pkH,
    const void* __restrict__ dbias,
    const unsigned short* __restrict__ att,
    const void* __restrict__ wq, const void* __restrict__ W1,
    const void* __restrict__ b1, const void* __restrict__ W2,
    const void* __restrict__ emb, const int* __restrict__ lens,
    void* __restrict__ dout,
    unsigned int* __restrict__ query_u,
    float* __restrict__ score_f,
    float* __restrict__ probs_f,
    float* __restrict__ ctx_f,
    unsigned int* __restrict__ z_u,
    int* __restrict__ flags, const int* dtf) {
  const int f32f = dtf[0];
  const int blk = blockIdx.x;
  const int tid = threadIdx.x;
  const int lane = tid & 63;
  const int wv = tid >> 6;
  __shared__ __align__(16) char smem[49152];

  const int gb = tid >> 3;
  const int gj = (tid & 7) * 2;
  float c0 = 0.f, c1 = 0.f, bv = 0.f;
  const int r0 = lane & 15;
  const int r1 = 16 + r0;
  const int kbb = (lane >> 4) * 8;
  const int nloc = wv * 16 + (lane & 15);
  if (blk < 32) {
    c0 = cdec[gb * HID + blk * 16 + gj];
    c1 = cdec[gb * HID + blk * 16 + gj + 1];
    int orow = (nloc >> 4) * HID + blk * 16 + (nloc & 15);
    bv = ldf(dbias, orow, f32f);
  }

  int ep = 0;
  auto gbar = [&]() {
    __syncthreads();   // vmcnt(0) drain: agent stores globally complete
    ++ep;
    if (tid < 64) {
      if (tid == 0)
        __hip_atomic_store(flags + blk * FLAG_STRIDE, ep, __ATOMIC_RELAXED,
                           __HIP_MEMORY_SCOPE_AGENT);
      for (;;) {
        int v0 = __hip_atomic_load(flags + tid * FLAG_STRIDE, __ATOMIC_RELAXED, __HIP_MEMORY_SCOPE_AGENT);
        int v1 = __hip_atomic_load(flags + (tid + 64) * FLAG_STRIDE, __ATOMIC_RELAXED, __HIP_MEMORY_SCOPE_AGENT);
        int v2 = __hip_atomic_load(flags + (tid + 128) * FLAG_STRIDE, __ATOMIC_RELAXED, __HIP_MEMORY_SCOPE_AGENT);
        int v3 = __hip_atomic_load(flags + (tid + 192) * FLAG_STRIDE, __ATOMIC_RELAXED, __HIP_MEMORY_SCOPE_AGENT);
        int mn = v0 < v1 ? v0 : v1;
        int mn2 = v2 < v3 ? v2 : v3;
        mn = mn < mn2 ? mn : mn2;
        if (__all(mn >= ep)) break;
        __builtin_amdgcn_s_sleep(4);
      }
    }
    __syncthreads();
  };

  for (int i = 0; i < TG; ++i) {
    unsigned short* hin = (i & 1) ? hd1 : hd0;
    unsigned short* hout = (i & 1) ? hd0 : hd1;

    // ---- P1: LSTM cell (blocks 0..31) ----
    if (blk < 32) {
      unsigned short* lstage = (unsigned short*)smem;
      float* gbuf = (float*)(smem + 32768);
      const unsigned int* xu = (const unsigned int*)xdec;
      unsigned int xreg[32];
#pragma unroll
      for (int it = 0; it < 32; ++it) xreg[it] = ald(xu + it * 256 + tid);
#pragma unroll
      for (int it = 0; it < 32; ++it) {
        int dw = it * 256 + tid;
        int row = dw >> 8;
        unsigned lb = (unsigned)(row * 1024 +
                                 (((dw & 252) << 2) ^ ((row & 7) << 4)) +
                                 ((dw & 3) << 2));
        *(unsigned int*)((char*)lstage + lb) = xreg[it];
      }
      __syncthreads();
      const unsigned int* hu = (const unsigned int*)hin;
      unsigned int hreg[32];
#pragma unroll
      for (int it = 0; it < 32; ++it) hreg[it] = ald(hu + it * 256 + tid);
      const int tile = blk * 4 + wv;
      const unsigned short* pwx = pkX + (size_t)tile * 16 * 64 * 8;
      const unsigned short* pwh = pkH + (size_t)tile * 16 * 64 * 8;
      f32x4 acc0 = {0.f, 0.f, 0.f, 0.f};
      f32x4 acc1 = {0.f, 0.f, 0.f, 0.f};
#pragma unroll
      for (int kk = 0; kk < 16; ++kk) {
        unsigned o0 = (unsigned)(r0 * 1024 + (((kk * 32 + kbb) * 2) ^ ((r0 & 7) << 4)));
        unsigned o1 = (unsigned)(r1 * 1024 + (((kk * 32 + kbb) * 2) ^ ((r0 & 7) << 4)));
        bf16x8 a0 = *(const bf16x8*)((const char*)lstage + o0);
        bf16x8 a1 = *(const bf16x8*)((const char*)lstage + o1);
        bf16x8 bb = *(const bf16x8*)(pwx + (size_t)(kk * 64 + lane) * 8);
        acc0 = __builtin_amdgcn_mfma_f32_16x16x32_bf16(a0, bb, acc0, 0, 0, 0);
        acc1 = __builtin_amdgcn_mfma_f32_16x16x32_bf16(a1, bb, acc1, 0, 0, 0);
      }
      __syncthreads();
#pragma unroll
      for (int it = 0; it < 32; ++it) {
        int dw = it * 256 + tid;
        int row = dw >> 8;
        unsigned lb = (unsigned)(row * 1024 +
                                 (((dw & 252) << 2) ^ ((row & 7) << 4)) +
                                 ((dw & 3) << 2));
        *(unsigned int*)((char*)lstage + lb) = hreg[it];
      }
      __syncthreads();
#pragma unroll
      for (int kk = 0; kk < 16; ++kk) {
        unsigned o0 = (unsigned)(r0 * 1024 + (((kk * 32 + kbb) * 2) ^ ((r0 & 7) << 4)));
        unsigned o1 = (unsigned)(r1 * 1024 + (((kk * 32 + kbb) * 2) ^ ((r0 & 7) << 4)));
        bf16x8 a0 = *(const bf16x8*)((const char*)lstage + o0);
        bf16x8 a1 = *(const bf16x8*)((const char*)lstage + o1);
        bf16x8 bb = *(const bf16x8*)(pwh + (size_t)(kk * 64 + lane) * 8);
        acc0 = __builtin_amdgcn_mfma_f32_16x16x32_bf16(a0, bb, acc0, 0, 0, 0);
        acc1 = __builtin_amdgcn_mfma_f32_16x16x32_bf16(a1, bb, acc1, 0, 0, 0);
      }
#pragma unroll
      for (int r = 0; r < 4; ++r) {
        int brow = (lane >> 4) * 4 + r;
        gbuf[brow * 68 + nloc] = acc0[r] + bv;
        gbuf[(16 + brow) * 68 + nloc] = acc1[r] + bv;
      }
      __syncthreads();
      {
        float gi0 = gbuf[gb * 68 + gj],      gf0 = gbuf[gb * 68 + 16 + gj];
        float gg0 = gbuf[gb * 68 + 32 + gj], go0 = gbuf[gb * 68 + 48 + gj];
        float gi1 = gbuf[gb * 68 + gj + 1],      gf1 = gbuf[gb * 68 + 16 + gj + 1];
        float gg1 = gbuf[gb * 68 + 32 + gj + 1], go1 = gbuf[gb * 68 + 48 + gj + 1];
        float cn0 = sigm(gf0) * c0 + sigm(gi0) * tanhf(gg0); c0 = cn0;
        float cn1 = sigm(gf1) * c1 + sigm(gi1) * tanhf(gg1); c1 = cn1;
        float hn0 = sigm(go0) * tanhf(cn0);
        float hn1 = sigm(go1) * tanhf(cn1);
        ast((unsigned int*)hout + gb * (HID / 2) + blk * 8 + (tid & 7),
            (unsigned int)f2b(hn0) | ((unsigned int)f2b(hn1) << 16));
        size_t e0 = ((size_t)gb * TG + i) * HID + blk * 16 + gj;
        stf(dout, OFF_H + e0, hn0, f32f);
        stf(dout, OFF_H + e0 + 1, hn1, f32f);
        stf(dout, OFF_C + e0, cn0, f32f);
        stf(dout, OFF_C + e0 + 1, cn1, f32f);
      }
    }
    gbar();

    // ---- P2: query = h @ wq (blocks 0..31, 16 cols each) ----
    if (blk < 32) {
      unsigned short* lh = (unsigned short*)smem;   // pitch 520 shorts
      const unsigned int* hu = (const unsigned int*)hout;
#pragma unroll
      for (int it = 0; it < 32; ++it) {
        int dw = it * 256 + tid;
        int b = dw >> 8, c = dw & 255;
        *(unsigned int*)(lh + b * 520 + c * 2) = ald(hu + dw);
      }
      __syncthreads();
      int b = tid >> 3, n = blk * 16 + (tid & 7) * 2;
      float a0 = 0.f, a1 = 0.f;
      for (int k = 0; k < HID; ++k) {
        float hv = b2f(lh[b * 520 + k]);
        a0 += hv * ldf(wq, (size_t)k * HID + n, f32f);
        a1 += hv * ldf(wq, (size_t)k * HID + n + 1, f32f);
      }
      ast(query_u + b * 256 + blk * 8 + (tid & 7),
          (unsigned int)f2b(a0) | ((unsigned int)f2b(a1) << 16));
    }
    gbar();

    // ---- P3: score (all 256 blocks, 4 t's each) ----
    {
      char* ql = smem;                              // pitch 1044 B per batch
#pragma unroll
      for (int it = 0; it < 32; ++it) {
        int dw = it * 256 + tid;
        int b = dw >> 8, c = dw & 255;
        *(unsigned int*)(ql + b * 1044 + c * 4) = ald(query_u + dw);
      }
      __syncthreads();
      int t = blk * 4 + wv;
      int b = lane >> 1, half = lane & 1;
      const unsigned short* arow = att + ((size_t)b * TS + t) * HID + half * 256;
      const unsigned short* qrow = (const unsigned short*)(ql + b * 1044) + half * 256;
      float s = 0.f;
#pragma unroll 4
      for (int j = 0; j < 32; ++j) {
        bf16x8 a8 = *(const bf16x8*)(arow + j * 8);
#pragma unroll
        for (int e = 0; e < 8; ++e)
          s += b2f(qrow[j * 8 + e]) * b2f(((const unsigned short*)&a8)[e]);
      }
      s += __shfl_xor(s, 1);
      if (half == 0) astf(score_f + (size_t)b * TS + t, s);
    }
    gbar();

    // ---- P4: softmax per batch (blocks 0..31) ----
    if (blk < 32) {
      float* red = (float*)smem;
      int b = blk, len = lens[b];
      float s[4], mx = -1e30f;
#pragma unroll
      for (int q = 0; q < 4; ++q) {
        int t = q * 256 + tid;
        float v = (t < len) ? aldf(score_f + (size_t)b * TS + t) : -1e30f;
        s[q] = v; mx = fmaxf(mx, v);
      }
      red[tid] = mx; __syncthreads();
      for (int st = 128; st; st >>= 1) { if (tid < st) red[tid] = fmaxf(red[tid], red[tid + st]); __syncthreads(); }
      mx = red[0]; __syncthreads();
      float e[4], sum = 0.f;
#pragma unroll
      for (int q = 0; q < 4; ++q) { e[q] = (s[q] > -1e29f) ? expf(s[q] - mx) : 0.f; sum += e[q]; }
      red[tid] = sum; __syncthreads();
      for (int st = 128; st; st >>= 1) { if (tid < st) red[tid] += red[tid + st]; __syncthreads(); }
      sum = red[0];
#pragma unroll
      for (int q = 0; q < 4; ++q)
        astf(probs_f + (size_t)b * TS + q * 256 + tid, e[q] / sum);
    }
    gbar();

    // ---- P5: context (256 blocks = 32 b x 8 col-chunks of 64) ----
    {
      int b = blk >> 3, hc = blk & 7;
      float* pl = (float*)smem;                     // 4 KB
      float* red = (float*)(smem + 4096);
#pragma unroll
      for (int q = 0; q < 4; ++q)
        pl[q * 256 + tid] = aldf(probs_f + (size_t)b * TS + q * 256 + tid);
      __syncthreads();
      int col = tid & 63, tq = tid >> 6;
      const unsigned short* abase = att + (size_t)b * TS * HID + hc * 64 + col;
      float acc = 0.f;
      for (int t = tq; t < TS; t += 4)
        acc += pl[t] * b2f(abase[(size_t)t * HID]);
      red[tq * 68 + col] = acc;
      __syncthreads();
      if (tid < 64) {
        float s = red[tid] + red[68 + tid] + red[136 + tid] + red[204 + tid];
        astf(ctx_f + (size_t)b * HID + hc * 64 + tid, s);
      }
    }
    gbar();

    // ---- P6: z = tanh([h|ctx] @ W1 + b1) (blocks 0..63, 8 cols each) ----
    if (blk < 64) {
      int b = tid >> 3, n = blk * 8 + (tid & 7);
      unsigned short* lh = (unsigned short*)smem;   // pitch 520 shorts
      const unsigned int* hu = (const unsigned int*)hout;
#pragma unroll
      for (int it = 0; it < 32; ++it) {
        int dw = it * 256 + tid;
        int bb = dw >> 8, c = dw & 255;
        *(unsigned int*)(lh + bb * 520 + c * 2) = ald(hu + dw);
      }
      __syncthreads();
      float acc = ldf(b1, n, f32f);
      for (int k = 0; k < HID; ++k)
        acc += b2f(lh[b * 520 + k]) * ldf(W1, (size_t)k * HID + n, f32f);
      __syncthreads();
      float* lc = (float*)smem;                     // pitch 260 f32
      for (int hlf = 0; hlf < 2; ++hlf) {
#pragma unroll
        for (int it = 0; it < 32; ++it) {
          int dw = it * 256 + tid;
          int bb = dw >> 8, c = dw & 255;
          // FIXED (R6 bug): stage ctx[bb][hlf*256 + c]
          lc[bb * 260 + c] = aldf(ctx_f + (size_t)bb * HID + hlf * 256 + c);
        }
        __syncthreads();
        for (int k2 = 0; k2 < 256; ++k2)
          acc += lc[b * 260 + k2] * ldf(W1, (size_t)(HID + hlf * 256 + k2) * HID + n, f32f);
        __syncthreads();
      }
      float z = tanhf(acc);
      unsigned short me = f2b(z);
      int other = __shfl_xor((int)me, 1);
      if ((tid & 1) == 0)
        ast(z_u + b * 256 + blk * 4 + ((tid & 7) >> 1),
            (unsigned int)me | ((unsigned int)(other & 0xffff) << 16));
    }
    gbar();

    // ---- P7: dec_out = z @ W2; write d_out + next-step xdec ----
    {
      int b = blk >> 3, mc = blk & 7;
      unsigned short* zl = (unsigned short*)smem;   // 1 KB
      float* rf = (float*)(smem + 1024);
      *(unsigned int*)(zl + tid * 2) = ald(z_u + b * 256 + tid);
      __syncthreads();
      int m_l = tid & 31, m = mc * 32 + m_l, kq = tid >> 5;
      float acc = 0.f;
      for (int kk = 0; kk < 64; ++kk) {
        int k = kq * 64 + kk;
        acc += b2f(zl[k]) * ldf(W2, (size_t)k * EDIM + m, f32f);
      }
      rf[kq * 36 + m_l] = acc;
      __syncthreads();
      if (tid < 32) {
        float s = 0.f;
#pragma unroll
        for (int q = 0; q < 8; ++q) s += rf[q * 36 + tid];
        stf(dout, ((size_t)b * TG + i) * EDIM + mc * 32 + tid, s, f32f);
        unsigned short mb = f2b(s);
        int ob = __shfl_xor((int)mb, 1);
        float ev = ldf(emb, (size_t)(SPECIAL + i + 1) * EDIM + mc * 32 + tid, f32f);
        unsigned short eb16 = f2b(ev);
        int oe = __shfl_xor((int)eb16, 1);
        if ((tid & 1) == 0) {
          unsigned int* xu = (unsigned int*)xdec;
          ast(xu + b * 256 + 128 + mc * 16 + (tid >> 1),
              (unsigned int)mb | ((unsigned int)(ob & 0xffff) << 16));
          ast(xu + b * 256 + mc * 16 + (tid >> 1),
              (unsigned int)eb16 | ((unsigned int)(oe & 0xffff) << 16));
        }
      }
    }
    gbar();
  }
}

__global__ __launch_bounds__(256) void attn_mm_k(
    const unsigned short* __restrict__ outF, const unsigned short* __restrict__ outB,
    const unsigned short* __restrict__ pkwm, unsigned short* __restrict__ att) {
  __shared__ char ldsA[4 * 1040];
  int bid = blockIdx.x;
  int bn = bid & 7, bm = bid >> 3;
  int tid = threadIdx.x, lane = tid & 63, wv = tid >> 6;
  int r0 = bm * 64;
  f32x4 acc[2][2] = {};
  int srow = tid >> 2, skb = tid & 3;
  int mt0 = (wv & 1) * 2, nt0 = (wv >> 1) * 2;
  for (int kk = 0; kk < 32; ++kk) {
    int kg = kk * 32 + skb * 8;
    const unsigned short* src = (kg < HID)
        ? (outF + (size_t)(r0 + srow) * HID + kg)
        : (outB + (size_t)(r0 + srow) * HID + (kg - HID));
    uint4 v = *(const uint4*)src;
    __syncthreads();
    *(uint4*)(ldsA + skb * 1040 + srow * 16) = v;
    __syncthreads();
    bf16x8 a[2], bb[2];
#pragma unroll
    for (int mi = 0; mi < 2; ++mi) {
      int rl = (mt0 + mi) * 16 + (lane & 15);
      a[mi] = *(const bf16x8*)(ldsA + (lane >> 4) * 1040 + rl * 16);
    }
#pragma unroll
    for (int nj = 0; nj < 2; ++nj) {
      int ntg = bn * 4 + nt0 + nj;
      bb[nj] = *(const bf16x8*)(pkwm + ((size_t)(ntg * 32 + kk) * 64 + lane) * 8);
    }
#pragma unroll
    for (int mi = 0; mi < 2; ++mi)
#pragma unroll
      for (int nj = 0; nj < 2; ++nj)
        acc[mi][nj] = __builtin_amdgcn_mfma_f32_16x16x32_bf16(a[mi], bb[nj], acc[mi][nj], 0, 0, 0);
  }
#pragma unroll
  for (int mi = 0; mi < 2; ++mi)
#pragma unroll
    for (int nj = 0; nj < 2; ++nj)
#pragma unroll
      for (int r = 0; r < 4; ++r) {
        int row = r0 + (mt0 + mi) * 16 + (lane >> 4) * 4 + r;
        int t = row >> 5, b = row & 31;
        int h = bn * 64 + (nt0 + nj) * 16 + (lane & 15);
        att[((size_t)b * TS + t) * HID + h] = f2b(acc[mi][nj][r]);
      }
}

__global__ void init_states_k(const void* __restrict__ ih, const void* __restrict__ ic,
                              unsigned short* hIF, unsigned short* hIB,
                              float* cF, float* cB, int* bar, const int* dtf) {
  int f32f = dtf[0];
  int g = blockIdx.x * 256 + threadIdx.x;
  if (g < (64 + 256) * FLAG_STRIDE)
    __hip_atomic_store(bar + g, 0, __ATOMIC_RELAXED, __HIP_MEMORY_SCOPE_AGENT);
  int b = g >> 9, j = g & 511;
  hIF[b * HID + j] = f2b(ldf(ih, j, f32f));
  hIB[b * HID + j] = f2b(ldf(ih, HID + j, f32f));
  cF[b * HID + j] = ldf(ic, j, f32f);
  cB[b * HID + j] = ldf(ic, HID + j, f32f);
}

__global__ void seqmean_k(const unsigned short* __restrict__ att,
                          const int* __restrict__ lens, float* __restrict__ sm) {
  int b = blockIdx.x, tid = threadIdx.x;
  int len = lens[b];
  float a0 = 0.f, a1 = 0.f;
  for (int t = 0; t < len; ++t) {
    const unsigned short* row = att + ((size_t)b * TS + t) * HID;
    a0 += b2f(row[tid]);
    a1 += b2f(row[tid + 256]);
  }
  float fl = (float)len;
  sm[b * HID + tid] = a0 / fl;
  sm[b * HID + tid + 256] = a1 / fl;
}

__global__ void mv_bb_k(const unsigned short* __restrict__ A1,
                        const unsigned short* __restrict__ A2,
                        const void* __restrict__ W, unsigned short* __restrict__ o,
                        const int* dtf) {
  int f32f = dtf[0];
  int g = blockIdx.x * 256 + threadIdx.x;
  int b = g >> 9, n = g & 511;
  float acc = 0.f;
  for (int k = 0; k < HID; ++k) acc += b2f(A1[b * HID + k]) * ldf(W, (size_t)k * HID + n, f32f);
  for (int k = 0; k < HID; ++k) acc += b2f(A2[b * HID + k]) * ldf(W, (size_t)(HID + k) * HID + n, f32f);
  o[b * HID + n] = f2b(acc);
}

__global__ void mv_ff_k(const float* __restrict__ A1, const float* __restrict__ A2,
                        const void* __restrict__ W, float* __restrict__ o, const int* dtf) {
  int f32f = dtf[0];
  int g = blockIdx.x * 256 + threadIdx.x;
  int b = g >> 9, n = g & 511;
  float acc = 0.f;
  for (int k = 0; k < HID; ++k) acc += A1[b * HID + k] * ldf(W, (size_t)k * HID + n, f32f);
  for (int k = 0; k < HID; ++k) acc += A2[b * HID + k] * ldf(W, (size_t)(HID + k) * HID + n, f32f);
  o[b * HID + n] = acc;
}

__global__ void proj1_k(const unsigned short* __restrict__ A1, const float* __restrict__ A2,
                        const void* __restrict__ W1p, const void* __restrict__ b1p,
                        unsigned short* __restrict__ z, const int* dtf) {
  int f32f = dtf[0];
  int g = blockIdx.x * 256 + threadIdx.x;
  int b = g >> 9, n = g & 511;
  float acc = ldf(b1p, n, f32f);
  for (int k = 0; k < HID; ++k) acc += b2f(A1[b * HID + k]) * ldf(W1p, (size_t)k * HID + n, f32f);
  for (int k = 0; k < HID; ++k) acc += A2[b * HID + k] * ldf(W1p, (size_t)(HID + k) * HID + n, f32f);
  z[b * HID + n] = f2b(tanhf(acc));
}

__global__ void proj2_init_k(const unsigned short* __restrict__ z,
                             const void* __restrict__ W2, const void* __restrict__ emb,
                             unsigned short* __restrict__ xdec, const int* dtf) {
  int f32f = dtf[0];
  int g = blockIdx.x * 256 + threadIdx.x;
  int b = g >> 8, n = g & 255;
  float acc = 0.f;
  for (int k = 0; k < HID; ++k) acc += b2f(z[b * HID + k]) * ldf(W2, (size_t)k * EDIM + n, f32f);
  xdec[b * HID + EDIM + n] = f2b(acc);
  xdec[b * HID + n] = f2b(ldf(emb, (size_t)SPECIAL * EDIM + n, f32f));
}

extern "C" void kernel_launch(void* const* d_in, const int* in_sizes, int n_in,
                              void* d_out, int out_size, void* d_ws, size_t ws_size,
                              hipStream_t stream) {
  (void)in_sizes; (void)n_in;
  const void* article = d_in[0];
  const int* art_lens = (const int*)d_in[1];
  const void* emb  = d_in[3];
  const void* eWxf = d_in[4]; const void* eWhf = d_in[5]; const void* ebf = d_in[6];
  const void* eWxb = d_in[7]; const void* eWhb = d_in[8]; const void* ebb = d_in[9];
  const void* initH = d_in[10]; const void* initC = d_in[11];
  const void* dhW = d_in[12]; const void* dcW = d_in[13];
  const void* wm = d_in[14]; const void* wq = d_in[15];
  const void* W1 = d_in[16]; const void* b1 = d_in[17]; const void* W2 = d_in[18];
  const void* dWx = d_in[19]; const void* dWh = d_in[20]; const void* db = d_in[21];

  char* ws = (char*)d_ws;
  size_t off = 0;
  auto take = [&](size_t bytes) -> char* {
    char* p = ws + off;
    off = (off + bytes + 255) & ~(size_t)255;
    return p;
  };
  int* dtf = (int*)take(4);
  int* bar = (int*)take((64 + 256) * FLAG_STRIDE * 4);
  unsigned short* pk_exf = (unsigned short*)take((size_t)GD * HID * 2);
  unsigned short* pk_ehf = (unsigned short*)take((size_t)GD * HID * 2);
  unsigned short* pk_exb = (unsigned short*)take((size_t)GD * HID * 2);
  unsigned short* pk_ehb = (unsigned short*)take((size_t)GD * HID * 2);
  unsigned short* pk_dx  = (unsigned short*)take((size_t)GD * HID * 2);
  unsigned short* pk_dh  = (unsigned short*)take((size_t)GD * HID * 2);
  unsigned short* pk_wm  = (unsigned short*)take((size_t)1024 * HID * 2);
  unsigned short* outF = (unsigned short*)take((size_t)TS * BATCH * HID * 2);
  unsigned short* outB = (unsigned short*)take((size_t)TS * BATCH * HID * 2);
  unsigned short* att  = (unsigned short*)take((size_t)BATCH * TS * HID * 2);
  unsigned short* hIF  = (unsigned short*)take((size_t)BATCH * HID * 2);
  unsigned short* hIB  = (unsigned short*)take((size_t)BATCH * HID * 2);
  float* cF = (float*)take((size_t)BATCH * HID * 4);
  float* cB = (float*)take((size_t)BATCH * HID * 4);
  unsigned short* hd0 = (unsigned short*)take((size_t)BATCH * HID * 2);
  unsigned short* hd1 = (unsigned short*)take((size_t)BATCH * HID * 2);
  float* cdec = (float*)take((size_t)BATCH * HID * 4);
  unsigned short* xdec = (unsigned short*)take((size_t)BATCH * HID * 2);
  unsigned short* zbuf = (unsigned short*)take((size_t)BATCH * HID * 2);
  unsigned int* query_u = (unsigned int*)take((size_t)BATCH * 256 * 4);
  float* scoreb = (float*)take((size_t)BATCH * TS * 4);
  float* probs = (float*)take((size_t)BATCH * TS * 4);
  float* ctx = (float*)take((size_t)BATCH * HID * 4);
  float* sm = (float*)take((size_t)BATCH * HID * 4);

  if (off > ws_size) {
    fill_sig_k<<<(out_size + 255) / 256, 256, 0, stream>>>((unsigned short*)d_out, out_size);
    return;
  }

  detect_k<<<1, 256, 0, stream>>>(article, dtf);
  pack_gate_k<<<512, 256, 0, stream>>>(eWxf, pk_exf, dtf);
  pack_gate_k<<<512, 256, 0, stream>>>(eWhf, pk_ehf, dtf);
  pack_gate_k<<<512, 256, 0, stream>>>(eWxb, pk_exb, dtf);
  pack_gate_k<<<512, 256, 0, stream>>>(eWhb, pk_ehb, dtf);
  pack_gate_k<<<512, 256, 0, stream>>>(dWx, pk_dx, dtf);
  pack_gate_k<<<512, 256, 0, stream>>>(dWh, pk_dh, dtf);
  pack_wm_k<<<256, 256, 0, stream>>>(wm, pk_wm, dtf);
  init_states_k<<<64, 256, 0, stream>>>(initH, initC, hIF, hIB, cF, cB, bar, dtf);

  enc_all_k<<<64, 256, 0, stream>>>(article, outF, outB, hIF, hIB, cF, cB,
                                    pk_exf, pk_ehf, pk_exb, pk_ehb, ebf, ebb,
                                    bar, dtf);

  attn_mm_k<<<4096, 256, 0, stream>>>(outF, outB, pk_wm, att);
  seqmean_k<<<32, 256, 0, stream>>>(att, art_lens, sm);
  mv_bb_k<<<64, 256, 0, stream>>>(outF + (size_t)(TS - 1) * BATCH * HID, outB, dhW, hd0, dtf);
  mv_ff_k<<<64, 256, 0, stream>>>(cF, cB, dcW, cdec, dtf);
  proj1_k<<<64, 256, 0, stream>>>(hd0, sm, W1, b1, zbuf, dtf);
  proj2_init_k<<<32, 256, 0, stream>>>(zbuf, W2, emb, xdec, dtf);

  dec_all_k<<<256, 256, 0, stream>>>(xdec, hd0, hd1, cdec, pk_dx, pk_dh, db,
                                     att, wq, W1, b1, W2, emb, art_lens, d_out,
                                     query_u, scoreb, probs, ctx,
                                     (unsigned int*)zbuf,
                                     bar + 64 * FLAG_STRIDE, dtf);
}